// Round 11
// baseline (495.259 us; speedup 1.0000x reference)
//
#include <hip/hip_runtime.h>
#include <cmath>

// ---------- constants ----------
#define IMG 131072        // 512*256 per batch image (elements; also u32/batch for packed planes)
#define BIGF 1048576      // 8*512*256

#define CF_RELU  1
#define CF_RES   2
#define CF_BN    4
#define CF_SPLIT 8
#define CF_TRANS 16

typedef __attribute__((ext_vector_type(8))) short short8;
typedef __attribute__((ext_vector_type(4))) short short4v;
typedef __attribute__((ext_vector_type(4))) float f32x4;

__device__ __forceinline__ float wave_sum(float v){
    #pragma unroll
    for (int off = 32; off; off >>= 1) v += __shfl_xor(v, off);
    return v;
}

__device__ __forceinline__ unsigned short bf16_rn(float x){
    union { float f; unsigned u; } v; v.f = x;
    unsigned r = v.u + 0x7FFF + ((v.u >> 16) & 1);
    return (unsigned short)(r >> 16);
}
__device__ __forceinline__ float bf16_to_f(unsigned short h){
    union { float f; unsigned u; } v; v.u = ((unsigned)h) << 16;
    return v.f;
}
__device__ __forceinline__ unsigned pack_split(float x){
    unsigned short hi = bf16_rn(x);
    unsigned short lo = bf16_rn(x - bf16_to_f(hi));
    return (unsigned)hi | ((unsigned)lo << 16);
}
// pack low16/high16 halves of two packed (hi|lo<<16) words:
// pk_hi(a,b) = {a.lo16, b.lo16}   pk_lo(a,b) = {a.hi16, b.hi16}
__device__ __forceinline__ unsigned pk_hi(unsigned a, unsigned b){
    return __builtin_amdgcn_perm(b, a, 0x05040100u);
}
__device__ __forceinline__ unsigned pk_lo(unsigned a, unsigned b){
    return __builtin_amdgcn_perm(b, a, 0x07060302u);
}

// ---------- job structs (paired launches across the two branches) ----------
struct GapJobs  { const float* x[2]; float* o[2]; };
struct G8Job    { const float* in; const float* W; const float* bias; const float* add; float* out; };
struct G8Jobs   { G8Job j[4]; };
struct AAJobs   { const float* qkv[2]; float* om[2]; };
struct LnJobs   { const float* in[2]; float* out[2]; };
struct UpJobs   { const float* in[2]; float* out[2]; };
struct SAJobs   { const float* q8[2]; const float* k8[2]; float* aw[2]; };
struct SPJobs   { const float* aw[2]; const float* v[2]; float* out[2]; };
struct ZJobs    { float* p[2]; };
struct ConvJob  { const float* X; const float* X2; const float* W; const float* B; const float* R;
                  const float* bng; const float* bnb; float* O; int flags; };
struct ConvJobs { ConvJob j[6]; };
struct PixJob   { const unsigned* Q; const unsigned* K; const unsigned* V; float* Oa; float* Ob; };
struct PixJobs  { PixJob j[2]; };

// ---------- GAP: mean over 256 spatial ----------
__global__ __launch_bounds__(64) void k_gap(GapJobs jo){
    const int br = blockIdx.y;
    const int bc = blockIdx.x;           // b*512 + c
    const int lane = threadIdx.x;
    const float* p = jo.x[br] + (size_t)bc * 256;
    float s = p[lane] + p[lane + 64] + p[lane + 128] + p[lane + 192];
    s = wave_sum(s);
    if (lane == 0) jo.o[br][bc] = s * (1.0f / 256.0f);
}

// ---------- tiny GEMM: out[8,O] = in[8,512] @ W[O,512]^T + bias (+add) ----------
__global__ __launch_bounds__(64) void k_gemm8(G8Jobs jo, int add_off, int add_stride, int O, int relu){
    const G8Job j = jo.j[blockIdx.y];
    const int o = blockIdx.x;
    const int lane = threadIdx.x;
    const float* wr = j.W + (size_t)o * 512;
    float acc[8] = {0,0,0,0,0,0,0,0};
    #pragma unroll
    for (int i = 0; i < 8; i++){
        float w = wr[lane + 64*i];
        #pragma unroll
        for (int b = 0; b < 8; b++) acc[b] += w * j.in[b*512 + lane + 64*i];
    }
    #pragma unroll
    for (int b = 0; b < 8; b++) acc[b] = wave_sum(acc[b]);
    if (lane < 8){
        float v = acc[0];
        #pragma unroll
        for (int b = 1; b < 8; b++) if (lane == b) v = acc[b];
        v += j.bias[o];
        if (j.add) v += j.add[lane*add_stride + add_off + o];
        if (relu) v = fmaxf(v, 0.f);
        j.out[(size_t)lane * O + o] = v;
    }
}

// ---------- asri batch-axis attention; writes merged o [8,512] ----------
__global__ __launch_bounds__(64) void k_asri_attn(AAJobs jo){
    const int br = blockIdx.y;
    const float* qkv = jo.qkv[br];
    const int h = blockIdx.x >> 3, b = blockIdx.x & 7, c = threadIdx.x;
    const int ci = c*8 + h;
    float qc = qkv[b*2048 + ci];
    float s[8];
    #pragma unroll
    for (int d = 0; d < 8; d++){
        float p = qc * qkv[d*2048 + 512 + ci];
        p = wave_sum(p);
        s[d] = p * 0.125f;
    }
    float m = s[0];
    #pragma unroll
    for (int d = 1; d < 8; d++) m = fmaxf(m, s[d]);
    float sum = 0.f;
    #pragma unroll
    for (int d = 0; d < 8; d++){ s[d] = __expf(s[d]-m); sum += s[d]; }
    float r = 1.f / sum;
    float oc = 0.f;
    #pragma unroll
    for (int d = 0; d < 8; d++) oc += s[d]*r * qkv[d*2048 + 1024 + ci];
    jo.om[br][b*512 + ci] = oc;
}

// ---------- LN over 512, 8 rows ----------
__global__ __launch_bounds__(64) void k_ln8(LnJobs jo,
    const float* __restrict__ g, const float* __restrict__ be)
{
    const int br = blockIdx.y;
    const int b = blockIdx.x, lane = threadIdx.x;
    const float* in = jo.in[br];
    float v[8]; float s = 0.f;
    #pragma unroll
    for (int i = 0; i < 8; i++){ v[i] = in[b*512 + lane + 64*i]; s += v[i]; }
    s = wave_sum(s);
    float mean = s * (1.f/512.f);
    float q = 0.f;
    #pragma unroll
    for (int i = 0; i < 8; i++){ float d = v[i]-mean; q += d*d; }
    q = wave_sum(q);
    float rstd = rsqrtf(q*(1.f/512.f) + 1e-5f);
    #pragma unroll
    for (int i = 0; i < 8; i++){
        int c = lane + 64*i;
        jo.out[br][b*512 + c] = (v[i]-mean)*rstd*g[c] + be[c];
    }
}

// ---------- bilinear upsample 4x4 -> 16x16 align_corners ----------
__global__ __launch_bounds__(256) void k_up(UpJobs jo){
    const int br = blockIdx.y;
    const int idx = blockIdx.x*256 + threadIdx.x;
    const int x = idx & 15, y = (idx >> 4) & 15, bc = idx >> 8;
    float px = (float)(x*3) / 15.0f, py = (float)(y*3) / 15.0f;
    int lx = (int)px, ly = (int)py;
    float wx = px - lx, wy = py - ly;
    int hx = min(lx+1, 3), hy = min(ly+1, 3);
    const float* p = jo.in[br] + (size_t)bc * 16;
    float v00 = p[ly*4+lx], v01 = p[ly*4+hx], v10 = p[hy*4+lx], v11 = p[hy*4+hx];
    float a0 = v00*(1.f-wy) + v10*wy;
    float a1 = v01*(1.f-wy) + v11*wy;
    jo.out[br][idx] = a0*(1.f-wx) + a1*wx;
}

// ---------- zero fill (fallback path only) ----------
__global__ __launch_bounds__(256) void k_zero(ZJobs jo){
    jo.p[blockIdx.y][(size_t)blockIdx.x*256 + threadIdx.x] = 0.f;
}

// ---------- conv1x1 via split-bf16 MFMA: 512 thr, K-split across 2 wave-groups ----------
// (proven kernel — used for the trans/split qkv dispatch, z=48: already 4 blocks/CU)
#define LDK 40
__device__ __forceinline__ void convm_body(
    const float* __restrict__ Xb, const float* __restrict__ X2b,
    const float* __restrict__ W,
    const float* __restrict__ bias, const float* __restrict__ resb,
    const float* __restrict__ bng, const float* __restrict__ bnb, float bninv,
    float* __restrict__ outb, int flags, int o0, int n0, unsigned short* lds)
{
    const int tid512 = threadIdx.x;
    const int g   = tid512 >> 8;          // K-group
    const int tid = tid512 & 255;
    unsigned short* sAh = lds + g*10240;
    unsigned short* sAl = sAh + 2560;
    unsigned short* sBh = sAl + 2560;
    unsigned short* sBl = sBh + 2560;
    const int wv = tid >> 6, lane = tid & 63;
    const int quad = lane >> 4, l16 = lane & 15;
    const int wo = (wv >> 1) * 32, wn = (wv & 1) * 32;
    const int so  = tid >> 2, sk8 = (tid & 3) * 8;
    const int sp  = tid & 15, sn  = (tid >> 4) * 4;

    const bool trans = (flags & CF_TRANS) != 0;
    int so_g = o0 + so;
    if (trans) so_g = ((so_g & 63) << 3) | (so_g >> 6);   // load W row for output position p

    const float* wrow = W + (size_t)so_g*512 + g*256 + sk8;
    const size_t xoff = (size_t)(g*256 + 2*sp)*256 + n0 + sn;
    const float* xrow  = Xb + xoff;
    const float* x2row = X2b ? X2b + xoff : nullptr;

    auto ldx4 = [&](size_t off){
        float4 v = *(const float4*)(xrow + off);
        if (x2row){
            float4 w2 = *(const float4*)(x2row + off);
            v.x += w2.x; v.y += w2.y; v.z += w2.z; v.w += w2.w;
        }
        return v;
    };

    f32x4 acc[2][2] = {};
    float4 a0 = *(const float4*)(wrow);
    float4 a1 = *(const float4*)(wrow + 4);
    float4 x0 = ldx4(0);
    float4 x1 = ldx4(256);

    for (int k0 = 0; k0 < 256; k0 += 32){
        __syncthreads();
        {
            float wa[8] = {a0.x,a0.y,a0.z,a0.w,a1.x,a1.y,a1.z,a1.w};
            #pragma unroll
            for (int j = 0; j < 4; j++){
                unsigned short h0 = bf16_rn(wa[2*j]);
                unsigned short h1 = bf16_rn(wa[2*j+1]);
                unsigned short g0 = bf16_rn(wa[2*j]   - bf16_to_f(h0));
                unsigned short g1 = bf16_rn(wa[2*j+1] - bf16_to_f(h1));
                *(unsigned*)&sAh[so*LDK + sk8 + 2*j] = (unsigned)h0 | ((unsigned)h1 << 16);
                *(unsigned*)&sAl[so*LDK + sk8 + 2*j] = (unsigned)g0 | ((unsigned)g1 << 16);
            }
            float xe[4] = {x0.x,x0.y,x0.z,x0.w};
            float xo[4] = {x1.x,x1.y,x1.z,x1.w};
            #pragma unroll
            for (int j = 0; j < 4; j++){
                unsigned short h0 = bf16_rn(xe[j]);
                unsigned short h1 = bf16_rn(xo[j]);
                unsigned short g0 = bf16_rn(xe[j] - bf16_to_f(h0));
                unsigned short g1 = bf16_rn(xo[j] - bf16_to_f(h1));
                *(unsigned*)&sBh[(sn+j)*LDK + 2*sp] = (unsigned)h0 | ((unsigned)h1 << 16);
                *(unsigned*)&sBl[(sn+j)*LDK + 2*sp] = (unsigned)g0 | ((unsigned)g1 << 16);
            }
        }
        __syncthreads();
        if (k0 + 32 < 256){
            a0 = *(const float4*)(wrow + k0 + 32);
            a1 = *(const float4*)(wrow + k0 + 36);
            x0 = ldx4((size_t)(k0+32)*256);
            x1 = ldx4((size_t)(k0+32)*256 + 256);
        }
        short8 ah[2], al[2], bh[2], bl[2];
        #pragma unroll
        for (int t = 0; t < 2; t++){
            int ai = (wo + 16*t + l16)*LDK + quad*8;
            ah[t] = *(const short8*)&sAh[ai];
            al[t] = *(const short8*)&sAl[ai];
            int bi = (wn + 16*t + l16)*LDK + quad*8;
            bh[t] = *(const short8*)&sBh[bi];
            bl[t] = *(const short8*)&sBl[bi];
        }
        if (trans){
            #pragma unroll
            for (int mt = 0; mt < 2; mt++){
                #pragma unroll
                for (int nt = 0; nt < 2; nt++){
                    acc[mt][nt] = __builtin_amdgcn_mfma_f32_16x16x32_bf16(bh[nt], ah[mt], acc[mt][nt], 0, 0, 0);
                    acc[mt][nt] = __builtin_amdgcn_mfma_f32_16x16x32_bf16(bl[nt], ah[mt], acc[mt][nt], 0, 0, 0);
                    acc[mt][nt] = __builtin_amdgcn_mfma_f32_16x16x32_bf16(bh[nt], al[mt], acc[mt][nt], 0, 0, 0);
                }
            }
        } else {
            #pragma unroll
            for (int mt = 0; mt < 2; mt++){
                #pragma unroll
                for (int nt = 0; nt < 2; nt++){
                    acc[mt][nt] = __builtin_amdgcn_mfma_f32_16x16x32_bf16(ah[mt], bh[nt], acc[mt][nt], 0, 0, 0);
                    acc[mt][nt] = __builtin_amdgcn_mfma_f32_16x16x32_bf16(ah[mt], bl[nt], acc[mt][nt], 0, 0, 0);
                    acc[mt][nt] = __builtin_amdgcn_mfma_f32_16x16x32_bf16(al[mt], bh[nt], acc[mt][nt], 0, 0, 0);
                }
            }
        }
    }
    // ---- cross-group reduction (stride-20 float rows: conflict-benign) ----
    __syncthreads();
    float* red = (float*)lds;
    if (g == 1){
        float* r = red + tid*20;
        #pragma unroll
        for (int mt = 0; mt < 2; mt++)
            #pragma unroll
            for (int nt = 0; nt < 2; nt++)
                *(f32x4*)(r + (mt*2+nt)*4) = acc[mt][nt];
    }
    __syncthreads();
    if (g == 0){
        float* r = red + tid*20;
        #pragma unroll
        for (int mt = 0; mt < 2; mt++)
            #pragma unroll
            for (int nt = 0; nt < 2; nt++){
                f32x4 o4 = *(const f32x4*)(r + (mt*2+nt)*4);
                acc[mt][nt] += o4;
            }
        if (trans){
            // rows = n (X free dim), cols = p (permuted W free dim) -> coalesced u32 stores
            unsigned* op = (unsigned*)outb;
            #pragma unroll
            for (int mt = 0; mt < 2; mt++){
                #pragma unroll
                for (int nt = 0; nt < 2; nt++){
                    const int p  = o0 + wo + 16*mt + l16;
                    const int nb = n0 + wn + 16*nt + quad*4;
                    const int osrc = ((p & 63) << 3) | (p >> 6);
                    const float bs = bias[osrc];
                    #pragma unroll
                    for (int rr = 0; rr < 4; rr++){
                        float v = acc[mt][nt][rr] + bs;
                        op[(size_t)(nb+rr)*512 + p] = pack_split(v);
                    }
                }
            }
        } else {
            #pragma unroll
            for (int mt = 0; mt < 2; mt++){
                #pragma unroll
                for (int nt = 0; nt < 2; nt++){
                    const int n  = n0 + wn + 16*nt + l16;
                    const int ob = o0 + wo + 16*mt + quad*4;
                    #pragma unroll
                    for (int rr = 0; rr < 4; rr++){
                        const int o = ob + rr;
                        float v = acc[mt][nt][rr] + bias[o];
                        if (flags & CF_BN)   v = v*(bninv*bng[o]) + bnb[o];
                        if (flags & CF_RELU) v = fmaxf(v, 0.f);
                        if (flags & CF_RES)  v += resb[(size_t)o*256 + n];
                        if (flags & CF_SPLIT){
                            ((unsigned*)outb)[(size_t)o*256 + n] = pack_split(v);
                        } else {
                            outb[(size_t)o*256 + n] = v;
                        }
                    }
                }
            }
        }
    }
}

__global__ __launch_bounds__(512) void k_convm(ConvJobs jo, float bninv)
{
    __shared__ unsigned short lds[20480];   // 40 KB: 2 groups x 4 planes x 64x40
    const int z = blockIdx.z;
    const ConvJob j = jo.j[z >> 3];
    const int b = z & 7;
    convm_body(j.X + (size_t)b*IMG,
               j.X2 ? j.X2 + (size_t)b*IMG : nullptr,
               j.W, j.B,
               j.R ? j.R + (size_t)b*IMG : nullptr,
               j.bng, j.bnb, bninv,
               j.O + (size_t)b*IMG, j.flags,
               blockIdx.y*64, blockIdx.x*64, lds);
}

// ---------- conv1x1 v2: 256 thr, o-tile 32, no K-split (plain f32 epilogue only) ----------
// Used for the five grid-limited z=16 dispatches (c2/v/a/pp/ln): 1024 blocks = 4 blocks/CU
// (2x the desynced barrier domains of the 512-block k_convm) and no cross-group reduction.
// Same split-bf16 MFMA triple in the same k-order as k_convm; K accumulates linearly over
// 512 (was 2 halves summed) - ulp-level reorder only. No CF_SPLIT/CF_TRANS paths.
__global__ __launch_bounds__(256) void k_convm2(ConvJobs jo, float bninv)
{
    __shared__ unsigned short lds[7680];   // 15 KB: A 32x40 + B 64x40, hi+lo planes
    const int z = blockIdx.z;
    const ConvJob j = jo.j[z >> 3];
    const int b = z & 7;
    const float* Xb   = j.X + (size_t)b*IMG;
    const float* X2b  = j.X2 ? j.X2 + (size_t)b*IMG : nullptr;
    const float* resb = j.R  ? j.R  + (size_t)b*IMG : nullptr;
    float* outb = j.O + (size_t)b*IMG;
    const int o0 = blockIdx.y*32, n0 = blockIdx.x*64;
    const int flags = j.flags;

    unsigned short* sAh = lds;            // [32 o][40]
    unsigned short* sAl = lds + 1280;
    unsigned short* sBh = lds + 2560;     // [64 n][40]
    unsigned short* sBl = lds + 5120;
    const int tid = threadIdx.x;
    const int wv = tid >> 6, lane = tid & 63;
    const int quad = lane >> 4, l16 = lane & 15;
    const int wo = (wv >> 1) * 16, wn = (wv & 1) * 32;
    const int so = tid >> 3, sk = (tid & 7) * 4;     // A-stage: 32 rows x 32 k
    const int sp = tid & 15, sn = (tid >> 4) * 4;    // B-stage: 64 n x 32 k

    const float* wrow = j.W + (size_t)(o0 + so)*512 + sk;
    const size_t xoff = (size_t)(2*sp)*256 + n0 + sn;
    const float* xrow  = Xb + xoff;
    const float* x2row = X2b ? X2b + xoff : nullptr;

    auto ldx4 = [&](size_t off){
        float4 v = *(const float4*)(xrow + off);
        if (x2row){
            float4 w2 = *(const float4*)(x2row + off);
            v.x += w2.x; v.y += w2.y; v.z += w2.z; v.w += w2.w;
        }
        return v;
    };

    f32x4 acc[2] = {};
    float4 a0 = *(const float4*)(wrow);
    float4 x0 = ldx4(0);
    float4 x1 = ldx4(256);

    for (int k0 = 0; k0 < 512; k0 += 32){
        __syncthreads();
        {
            unsigned short h0 = bf16_rn(a0.x);
            unsigned short h1 = bf16_rn(a0.y);
            unsigned short g0 = bf16_rn(a0.x - bf16_to_f(h0));
            unsigned short g1 = bf16_rn(a0.y - bf16_to_f(h1));
            *(unsigned*)&sAh[so*40 + sk]     = (unsigned)h0 | ((unsigned)h1 << 16);
            *(unsigned*)&sAl[so*40 + sk]     = (unsigned)g0 | ((unsigned)g1 << 16);
            h0 = bf16_rn(a0.z);
            h1 = bf16_rn(a0.w);
            g0 = bf16_rn(a0.z - bf16_to_f(h0));
            g1 = bf16_rn(a0.w - bf16_to_f(h1));
            *(unsigned*)&sAh[so*40 + sk + 2] = (unsigned)h0 | ((unsigned)h1 << 16);
            *(unsigned*)&sAl[so*40 + sk + 2] = (unsigned)g0 | ((unsigned)g1 << 16);

            float xe[4] = {x0.x,x0.y,x0.z,x0.w};
            float xo[4] = {x1.x,x1.y,x1.z,x1.w};
            #pragma unroll
            for (int jj = 0; jj < 4; jj++){
                unsigned short e0 = bf16_rn(xe[jj]);
                unsigned short e1 = bf16_rn(xo[jj]);
                unsigned short f0 = bf16_rn(xe[jj] - bf16_to_f(e0));
                unsigned short f1 = bf16_rn(xo[jj] - bf16_to_f(e1));
                *(unsigned*)&sBh[(sn+jj)*40 + 2*sp] = (unsigned)e0 | ((unsigned)e1 << 16);
                *(unsigned*)&sBl[(sn+jj)*40 + 2*sp] = (unsigned)f0 | ((unsigned)f1 << 16);
            }
        }
        __syncthreads();
        if (k0 + 32 < 512){
            a0 = *(const float4*)(wrow + k0 + 32);
            x0 = ldx4((size_t)(k0+32)*256);
            x1 = ldx4((size_t)(k0+32)*256 + 256);
        }
        short8 ah, al, bh0, bl0, bh1, bl1;
        {
            int ai = (wo + l16)*40 + quad*8;
            ah = *(const short8*)&sAh[ai];
            al = *(const short8*)&sAl[ai];
        }
        {
            int bi = (wn + l16)*40 + quad*8;
            bh0 = *(const short8*)&sBh[bi];
            bl0 = *(const short8*)&sBl[bi];
        }
        {
            int bi = (wn + 16 + l16)*40 + quad*8;
            bh1 = *(const short8*)&sBh[bi];
            bl1 = *(const short8*)&sBl[bi];
        }
        acc[0] = __builtin_amdgcn_mfma_f32_16x16x32_bf16(ah, bh0, acc[0], 0, 0, 0);
        acc[0] = __builtin_amdgcn_mfma_f32_16x16x32_bf16(ah, bl0, acc[0], 0, 0, 0);
        acc[0] = __builtin_amdgcn_mfma_f32_16x16x32_bf16(al, bh0, acc[0], 0, 0, 0);
        acc[1] = __builtin_amdgcn_mfma_f32_16x16x32_bf16(ah, bh1, acc[1], 0, 0, 0);
        acc[1] = __builtin_amdgcn_mfma_f32_16x16x32_bf16(ah, bl1, acc[1], 0, 0, 0);
        acc[1] = __builtin_amdgcn_mfma_f32_16x16x32_bf16(al, bh1, acc[1], 0, 0, 0);
    }
    // ---- epilogue: every wave writes its own 16(o) x 32(n) tile ----
    #pragma unroll
    for (int nt = 0; nt < 2; nt++){
        const int n  = n0 + wn + 16*nt + l16;
        const int ob = o0 + wo + quad*4;
        #pragma unroll
        for (int rr = 0; rr < 4; rr++){
            const int o = ob + rr;
            float v = acc[nt][rr] + j.B[o];
            if (flags & CF_BN)   v = v*(bninv*j.bng[o]) + j.bnb[o];
            if (flags & CF_RELU) v = fmaxf(v, 0.f);
            if (flags & CF_RES)  v += resb[(size_t)o*256 + n];
            outb[(size_t)o*256 + n] = v;
        }
    }
}

// ---------- sscm attention weights [h][b][d] ----------
__global__ __launch_bounds__(64) void k_sscm_attn(SAJobs jo)
{
    const int br = blockIdx.y;
    const int h = blockIdx.x >> 3, b = blockIdx.x & 7, c = threadIdx.x;
    const int ci = c*8 + h;
    float qc = jo.q8[br][b*512 + ci];
    float s[8];
    #pragma unroll
    for (int d = 0; d < 8; d++){
        float p = qc * jo.k8[br][d*512 + ci];
        p = wave_sum(p);
        s[d] = p * 0.125f;
    }
    float m = s[0];
    #pragma unroll
    for (int d = 1; d < 8; d++) m = fmaxf(m, s[d]);
    float sum = 0.f;
    #pragma unroll
    for (int d = 0; d < 8; d++){ s[d] = __expf(s[d]-m); sum += s[d]; }
    float r = 1.f/sum;
    if (c < 8){
        float v = s[0];
        #pragma unroll
        for (int d = 1; d < 8; d++) if (c == d) v = s[d];
        jo.aw[br][blockIdx.x*8 + c] = v*r;
    }
}

// ---------- sscm apply ----------
__global__ __launch_bounds__(256) void k_sscm_apply(SPJobs jo)
{
    const int br = blockIdx.y;
    const int idx = blockIdx.x*256 + threadIdx.x;
    const int pix = idx & 255, e = (idx >> 8) & 511, b = idx >> 17;
    const int h = e & 7;
    const float* aw = jo.aw[br] + (h*8 + b)*8;
    const float* v = jo.v[br];
    float acc = 0.f;
    #pragma unroll
    for (int d = 0; d < 8; d++) acc += aw[d] * v[(size_t)d*IMG + (size_t)e*256 + pix];
    jo.out[br][idx] = acc;
}

// ---------- pixel cross-batch attention, v7 (round-7 proven: T14 async-STAGE + setprio) ----------
__global__ __launch_bounds__(256) void k_pixel_mfma(PixJobs jo)
{
    __shared__ char smem[40960];
    unsigned short* sQh = (unsigned short*)smem;      // [2 ks][64 q][40]      5120 ush
    unsigned short* sQl = sQh + 2*64*40;              //                       5120
    unsigned short* sKh = sQl + 2*64*40;              // [2 chan-ks][64 m][40] 5120
    unsigned short* sKl = sKh + 2*64*40;              //                       5120
    unsigned short* sP  = (unsigned short*)smem;      // [4 mks][64 q][40] aliases Q region
    unsigned short* sVh = sKh;                        // [2 mks][64 c][40] aliases K region
    unsigned short* sVl = sKl;

    const int br = blockIdx.y >> 3, b = blockIdx.y & 7;
    const PixJob J = jo.j[br];
    const int nt = blockIdx.x & 3, dg = blockIdx.x >> 2;
    const int h = blockIdx.z;
    const int tid = threadIdx.x;
    const int wv = tid >> 6, lane = tid & 63;
    const int quad = lane >> 4, l16 = lane & 15;
    const int n0 = nt * 64;

    // ---- stage Q once: [n0+q][h*64 + i], channel-contiguous vector loads ----
    {
        const unsigned* Qt = J.Q + (size_t)b*IMG + (size_t)n0*512 + h*64;
        const int q = tid >> 2, i0 = (tid & 3) * 16;
        const unsigned* src = Qt + (size_t)q*512 + i0;
        uint4 w0 = *(const uint4*)(src);
        uint4 w1 = *(const uint4*)(src + 4);
        uint4 w2 = *(const uint4*)(src + 8);
        uint4 w3 = *(const uint4*)(src + 12);
        unsigned hb[8], lb[8];
        hb[0]=pk_hi(w0.x,w0.y); hb[1]=pk_hi(w0.z,w0.w); hb[2]=pk_hi(w1.x,w1.y); hb[3]=pk_hi(w1.z,w1.w);
        hb[4]=pk_hi(w2.x,w2.y); hb[5]=pk_hi(w2.z,w2.w); hb[6]=pk_hi(w3.x,w3.y); hb[7]=pk_hi(w3.z,w3.w);
        lb[0]=pk_lo(w0.x,w0.y); lb[1]=pk_lo(w0.z,w0.w); lb[2]=pk_lo(w1.x,w1.y); lb[3]=pk_lo(w1.z,w1.w);
        lb[4]=pk_lo(w2.x,w2.y); lb[5]=pk_lo(w2.z,w2.w); lb[6]=pk_lo(w3.x,w3.y); lb[7]=pk_lo(w3.z,w3.w);
        int dst = (i0>>5)*2560 + q*40 + (i0&31);
        *(uint4*)&sQh[dst]     = *(uint4*)&hb[0];
        *(uint4*)&sQh[dst + 8] = *(uint4*)&hb[4];
        *(uint4*)&sQl[dst]     = *(uint4*)&lb[0];
        *(uint4*)&sQl[dst + 8] = *(uint4*)&lb[4];
    }
    __syncthreads();

    short8 bqh[2], bql[2];
    #pragma unroll
    for (int ks = 0; ks < 2; ks++){
        int idx = ks*2560 + (wv*16 + l16)*40 + quad*8;
        bqh[ks] = *(const short8*)&sQh[idx];
        bql[ks] = *(const short8*)&sQl[idx];
    }

    // ---- prefetch machinery: one 16-VGPR buffer, time-shared K/V ----
    const int mloc = tid & 63, cb0 = tid >> 6;   // K staging coords
    const int mp = tid & 31,  c0v = tid >> 5;    // V staging coords
    uint4 pf[4];

    auto loadK = [&](int d, int mq){
        const unsigned* Kt = J.K + (size_t)d*IMG + (size_t)(mq*64 + mloc)*512 + h*64;
        pf[0] = *(const uint4*)(Kt + cb0*8);
        pf[1] = *(const uint4*)(Kt + cb0*8 + 4);
        pf[2] = *(const uint4*)(Kt + (cb0+4)*8);
        pf[3] = *(const uint4*)(Kt + (cb0+4)*8 + 4);
    };
    auto writeK = [&](){
        #pragma unroll
        for (int p = 0; p < 2; p++){
            uint4 wa = pf[2*p], wb = pf[2*p+1];
            union { short8 s; unsigned u[4]; } hu, lu;
            hu.u[0]=pk_hi(wa.x,wa.y); hu.u[1]=pk_hi(wa.z,wa.w);
            hu.u[2]=pk_hi(wb.x,wb.y); hu.u[3]=pk_hi(wb.z,wb.w);
            lu.u[0]=pk_lo(wa.x,wa.y); lu.u[1]=pk_lo(wa.z,wa.w);
            lu.u[2]=pk_lo(wb.x,wb.y); lu.u[3]=pk_lo(wb.z,wb.w);
            int cb = cb0 + 4*p;
            int idx = (cb>>2)*2560 + mloc*40 + (cb&3)*8;
            *(short8*)&sKh[idx] = hu.s;
            *(short8*)&sKl[idx] = lu.s;
        }
    };
    auto loadV = [&](int d, int vs){
        const unsigned* Vp = J.V + (size_t)d*IMG + (size_t)h*256 + (vs>>1)*128 + (vs&1)*64 + 2*mp;
        #pragma unroll
        for (int p2 = 0; p2 < 4; p2++){
            uint2 wA = *(const uint2*)(Vp + (size_t)(c0v + 16*p2)*2048);
            uint2 wB = *(const uint2*)(Vp + (size_t)(c0v + 16*p2 + 8)*2048);
            pf[p2].x = wA.x; pf[p2].y = wA.y; pf[p2].z = wB.x; pf[p2].w = wB.y;
        }
    };
    auto writeV = [&](){
        const int ib = ((2*mp)>>5)*2560 + ((2*mp)&31);
        #pragma unroll
        for (int p2 = 0; p2 < 4; p2++){
            int ca = c0v + 16*p2, cb2 = ca + 8;
            *(unsigned*)&sVh[ib + ca*40]  = pk_hi(pf[p2].x, pf[p2].y);
            *(unsigned*)&sVl[ib + ca*40]  = pk_lo(pf[p2].x, pf[p2].y);
            *(unsigned*)&sVh[ib + cb2*40] = pk_hi(pf[p2].z, pf[p2].w);
            *(unsigned*)&sVl[ib + cb2*40] = pk_lo(pf[p2].z, pf[p2].w);
        }
    };

    f32x4 oac[4] = {};
    loadK(dg*4, 0);   // prime the pipeline

    for (int dd = 0; dd < 4; dd++){
        const int d = dg*4 + dd;

        // ---- S = Q @ K^T, 4 m-quarters; K prefetched one phase ahead ----
        f32x4 S[16] = {};
        #pragma unroll
        for (int mq = 0; mq < 4; mq++){
            if (mq | dd) __syncthreads();   // prior sK(S)/sV(PV) reads done
            writeK();
            if (mq < 3) loadK(d, mq+1);     // in flight during barrier+MFMA below
            else        loadV(d, 0);        // V(vs=0) hidden under last MFMA + softmax
            __syncthreads();
            __builtin_amdgcn_s_setprio(1);
            #pragma unroll
            for (int mtl = 0; mtl < 4; mtl++){
                int t = mq*4 + mtl;
                #pragma unroll
                for (int ks = 0; ks < 2; ks++){
                    int idx = ks*2560 + (mtl*16 + l16)*40 + quad*8;
                    short8 ah = *(const short8*)&sKh[idx];
                    short8 al = *(const short8*)&sKl[idx];
                    S[t] = __builtin_amdgcn_mfma_f32_16x16x32_bf16(ah, bqh[ks], S[t], 0, 0, 0);
                    S[t] = __builtin_amdgcn_mfma_f32_16x16x32_bf16(ah, bql[ks], S[t], 0, 0, 0);
                    S[t] = __builtin_amdgcn_mfma_f32_16x16x32_bf16(al, bqh[ks], S[t], 0, 0, 0);
                }
            }
            __builtin_amdgcn_s_setprio(0);
        }

        // ---- softmax over this key batch's 256 m (exact, per reference) ----
        {
            float mx = -3.4e38f;
            #pragma unroll
            for (int t = 0; t < 16; t++)
                #pragma unroll
                for (int r = 0; r < 4; r++) mx = fmaxf(mx, S[t][r]);
            mx = fmaxf(mx, __shfl_xor(mx, 16));
            mx = fmaxf(mx, __shfl_xor(mx, 32));
            float sum = 0.f;
            #pragma unroll
            for (int t = 0; t < 16; t++)
                #pragma unroll
                for (int r = 0; r < 4; r++){ S[t][r] = __expf(S[t][r]-mx); sum += S[t][r]; }
            sum += __shfl_xor(sum, 16);
            sum += __shfl_xor(sum, 32);
            float rr = 1.f/sum;
            #pragma unroll
            for (int t = 0; t < 16; t++)
                #pragma unroll
                for (int r = 0; r < 4; r++) S[t][r] *= rr;
        }

        // ---- O += P @ V, vs-linear (hm=vs>>1, sub=vs&1); V prefetched one phase ahead ----
        #pragma unroll
        for (int vs = 0; vs < 4; vs++){
            __syncthreads();   // prior sK(S last mq)/sP/sV reads done
            if ((vs & 1) == 0){
                const int hm = vs >> 1;
                #pragma unroll
                for (int mtl = 0; mtl < 8; mtl++){
                    int t = hm*8 + mtl;
                    short4v p4;
                    #pragma unroll
                    for (int r = 0; r < 4; r++) p4[r] = (short)bf16_rn(S[t][r]);
                    int idx = (mtl>>1)*2560 + (wv*16 + l16)*40 + 16*(mtl&1) + quad*4;
                    *(short4v*)&sP[idx] = p4;
                }
            }
            writeV();
            if (vs < 3)      loadV(d, vs+1);      // in flight during barrier+MFMA below
            else if (dd < 3) loadK(d+1, 0);       // next key batch's first K quarter
            __syncthreads();
            __builtin_amdgcn_s_setprio(1);
            #pragma unroll
            for (int l = 0; l < 2; l++){
                int gks = (vs & 1)*2 + l;
                int pidx = gks*2560 + (wv*16 + l16)*40 + quad*8;
                short8 bp = *(const short8*)&sP[pidx];
                #pragma unroll
                for (int ct = 0; ct < 4; ct++){
                    int vidx = l*2560 + (ct*16 + l16)*40 + quad*8;
                    short8 vh = *(const short8*)&sVh[vidx];
                    short8 vl = *(const short8*)&sVl[vidx];
                    oac[ct] = __builtin_amdgcn_mfma_f32_16x16x32_bf16(vh, bp, oac[ct], 0, 0, 0);
                    oac[ct] = __builtin_amdgcn_mfma_f32_16x16x32_bf16(vl, bp, oac[ct], 0, 0, 0);
                }
            }
            __builtin_amdgcn_s_setprio(0);
        }
    }

    // ---- single output: plain store to this d-group's partial buffer ----
    {
        float* base = (J.Ob ? (dg ? J.Ob : J.Oa) : J.Oa);
        float* Obp = base + (size_t)b * IMG;
        const int q = n0 + wv*16 + l16;
        if (J.Ob){
            #pragma unroll
            for (int ct = 0; ct < 4; ct++){
                #pragma unroll
                for (int r = 0; r < 4; r++){
                    int c = ct*16 + quad*4 + r;
                    Obp[(size_t)(c*8+h)*256 + q] = oac[ct][r];
                }
            }
        } else {
            #pragma unroll
            for (int ct = 0; ct < 4; ct++){
                #pragma unroll
                for (int r = 0; r < 4; r++){
                    int c = ct*16 + quad*4 + r;
                    unsafeAtomicAdd(&Obp[(size_t)(c*8+h)*256 + q], oac[ct][r]);
                }
            }
        }
    }
}

// ---------- LN over channels (strided), keeps [b][c][n] layout ----------
__global__ __launch_bounds__(64) void k_ln_pix(LnJobs jo,
    const float* __restrict__ g, const float* __restrict__ be)
{
    const int br = blockIdx.y;
    const int bn = blockIdx.x;
    const int b = bn >> 8, n = bn & 255;
    const int lane = threadIdx.x;
    const float* p = jo.in[br] + (size_t)b*IMG + n;
    float v[8]; float s = 0.f;
    #pragma unroll
    for (int i = 0; i < 8; i++){ v[i] = p[(size_t)(lane + 64*i)*256]; s += v[i]; }
    s = wave_sum(s);
    float mean = s * (1.f/512.f);
    float q = 0.f;
    #pragma unroll
    for (int i = 0; i < 8; i++){ float d = v[i]-mean; q += d*d; }
    q = wave_sum(q);
    float rstd = rsqrtf(q*(1.f/512.f) + 1e-5f);
    #pragma unroll
    for (int i = 0; i < 8; i++){
        int c = lane + 64*i;
        jo.out[br][(size_t)b*IMG + (size_t)c*256 + n] = (v[i]-mean)*rstd*g[c] + be[c];
    }
}

// ---------- host orchestration ----------
extern "C" void kernel_launch(void* const* d_in, const int* in_sizes, int n_in,
                              void* d_out, int out_size, void* d_ws, size_t ws_size,
                              hipStream_t stream)
{
    const float* xs    = (const float*)d_in[0];
    const float* xq    = (const float*)d_in[1];
    const float* qkvw  = (const float*)d_in[2];  const float* qkvb = (const float*)d_in[3];
    const float* paw   = (const float*)d_in[4];  const float* pab  = (const float*)d_in[5];
    const float* ln1g  = (const float*)d_in[6];  const float* ln1b = (const float*)d_in[7];
    const float* f1w   = (const float*)d_in[8];  const float* f1b  = (const float*)d_in[9];
    const float* f2w   = (const float*)d_in[10]; const float* f2b  = (const float*)d_in[11];
    const float* ln2g  = (const float*)d_in[12]; const float* ln2b = (const float*)d_in[13];
    const float* c1w   = (const float*)d_in[14]; const float* c1b  = (const float*)d_in[15];
    const float* c2w   = (const float*)d_in[16]; const float* c2b  = (const float*)d_in[17];
    const float* bng   = (const float*)d_in[18]; const float* bnb  = (const float*)d_in[19];
    const float* caqw  = (const float*)d_in[20]; const float* caqb = (const float*)d_in[21];
    const float* cakw  = (const float*)d_in[22]; const float* cakb = (const float*)d_in[23];
    const float* cavw  = (const float*)d_in[24]; const float* cavb = (const float*)d_in[25];
    const float* capw  = (const float*)d_in[26]; const float* capb = (const float*)d_in[27];
    const float* pqw   = (const float*)d_in[28]; const float* pqb  = (const float*)d_in[29];
    const float* pkw   = (const float*)d_in[30]; const float* pkb  = (const float*)d_in[31];
    const float* pvw   = (const float*)d_in[32]; const float* pvb  = (const float*)d_in[33];
    const float* ppw   = (const float*)d_in[34]; const float* ppb  = (const float*)d_in[35];
    const float* plng  = (const float*)d_in[36]; const float* plnb = (const float*)d_in[37];
    const float* plinw = (const float*)d_in[38]; const float* plinb= (const float*)d_in[39];

    const size_t SMF = 262144;  // small-scratch floats (2 branch regions of 131072)
    float* ws = (float*)d_ws;
    float* smb = ws;
    float* B[14];
    for (int i = 0; i < 14; i++) B[i] = ws + SMF + (size_t)i*BIGF;
    float* sa_s = B[0]; float* sa_q = B[1];
    float* ca_s = B[2]; float* ca_q = B[3];
    const bool paired_pixel = ws_size >= (SMF + 12*(size_t)BIGF)*sizeof(float) + 1024;
    const bool has_dsplit   = ws_size >= (SMF + 14*(size_t)BIGF)*sizeof(float) + 1024;

    auto SM = [&](int br){ return smb + (size_t)br*131072; };
    // per-branch small offsets
    auto GAP=[&](int br){ return SM(br); };            auto QKV=[&](int br){ return SM(br)+4096; };
    auto OM =[&](int br){ return SM(br)+20480; };      auto AA =[&](int br){ return SM(br)+24576; };
    auto HB =[&](int br){ return SM(br)+28672; };      auto A2 =[&](int br){ return SM(br)+32768; };
    auto LNB=[&](int br){ return SM(br)+36864; };      auto S8 =[&](int br){ return SM(br)+40960; };
    auto ATW=[&](int br){ return SM(br)+106496; };     auto Q8 =[&](int br){ return SM(br)+107008; };
    auto K8 =[&](int br){ return SM(br)+111104; };

    const float bninv = 1.0f / sqrtf(1.0f + 1e-5f);
    float* out0 = (float*)d_out;
    float* out1 = out0 + (size_t)BIGF;

    // ================= ASRI (both branches paired) =================
    {
        GapJobs gj = {{xs, xq}, {GAP(0), GAP(1)}};
        k_gap<<<dim3(4096,2), 64, 0, stream>>>(gj);
        G8Jobs qj = {{{GAP(0), qkvw, qkvb, nullptr, QKV(0)}, {GAP(1), qkvw, qkvb, nullptr, QKV(1)}}};
        k_gemm8<<<dim3(2048,2), 64, 0, stream>>>(qj, 0, 0, 2048, 0);
        AAJobs aj = {{QKV(0), QKV(1)}, {OM(0), OM(1)}};
        k_asri_attn<<<dim3(64,2), 64, 0, stream>>>(aj);
        G8Jobs pj = {{{OM(0), paw, pab, QKV(0), AA(0)}, {OM(1), paw, pab, QKV(1), AA(1)}}};
        k_gemm8<<<dim3(512,2), 64, 0, stream>>>(pj, 1536, 2048, 512, 0);
        LnJobs l1 = {{AA(0), AA(1)}, {LNB(0), LNB(1)}};
        k_ln8<<<dim3(8,2), 64, 0, stream>>>(l1, ln1g, ln1b);
        G8Jobs fj = {{{LNB(0), f1w, f1b, nullptr, HB(0)}, {LNB(1), f1w, f1b, nullptr, HB(1)}}};
        k_gemm8<<<dim3(512,2), 64, 0, stream>>>(fj, 0, 0, 512, 1);
        G8Jobs f2j = {{{HB(0), f2w, f2b, AA(0), A2(0)}, {HB(1), f2w, f2b, AA(1), A2(1)}}};
        k_gemm8<<<dim3(512,2), 64, 0, stream>>>(f2j, 0, 512, 512, 0);
        LnJobs l2 = {{A2(0), A2(1)}, {LNB(0), LNB(1)}};
        k_ln8<<<dim3(8,2), 64, 0, stream>>>(l2, ln2g, ln2b);
        G8Jobs cj = {{{LNB(0), c1w, c1b, nullptr, S8(0)}, {LNB(1), c1w, c1b, nullptr, S8(1)}}};
        k_gemm8<<<dim3(8192,2), 64, 0, stream>>>(cj, 0, 0, 8192, 0);
        UpJobs uj = {{S8(0), S8(1)}, {B[4], B[5]}};
        k_up<<<dim3(4096,2), 256, 0, stream>>>(uj);
        ConvJobs c2j = {};
        c2j.j[0] = {B[4], nullptr, c2w, c2b, xs, bng, bnb, sa_s, CF_BN|CF_RELU|CF_RES};
        c2j.j[1] = {B[5], nullptr, c2w, c2b, xq, bng, bnb, sa_q, CF_BN|CF_RELU|CF_RES};
        k_convm2<<<dim3(4,16,16), 256, 0, stream>>>(c2j, bninv);
    }

    // ================= SSCM (both branches paired) =================
    {
        GapJobs gj = {{sa_s, sa_q}, {GAP(0), GAP(1)}};   // gap0 = gap(sa_s), gap1 = gap(sa_q)
        k_gap<<<dim3(4096,2), 64, 0, stream>>>(gj);
        G8Jobs qj = {{{GAP(0), caqw, caqb, nullptr, Q8(0)},   // br0: q from sa_s
                      {GAP(1), cakw, cakb, nullptr, K8(0)},   // br0: k from sa_q
                      {GAP(1), caqw, caqb, nullptr, Q8(1)},   // br1: q from sa_q
                      {GAP(0), cakw, cakb, nullptr, K8(1)}}}; // br1: k from sa_s
        k_gemm8<<<dim3(512,4), 64, 0, stream>>>(qj, 0, 0, 512, 0);
        SAJobs sj = {{Q8(0), Q8(1)}, {K8(0), K8(1)}, {ATW(0), ATW(1)}};
        k_sscm_attn<<<dim3(64,2), 64, 0, stream>>>(sj);
        ConvJobs vj = {};
        vj.j[0] = {sa_q, nullptr, cavw, cavb, nullptr, nullptr, nullptr, B[4], 0};
        vj.j[1] = {sa_s, nullptr, cavw, cavb, nullptr, nullptr, nullptr, B[5], 0};
        k_convm2<<<dim3(4,16,16), 256, 0, stream>>>(vj, 1.f);
        SPJobs pj = {{ATW(0), ATW(1)}, {B[4], B[5]}, {B[6], B[7]}};
        k_sscm_apply<<<dim3(4096,2), 256, 0, stream>>>(pj);
        ConvJobs aj = {};
        aj.j[0] = {B[6], nullptr, capw, capb, nullptr, nullptr, nullptr, ca_s, CF_RELU};
        aj.j[1] = {B[7], nullptr, capw, capb, nullptr, nullptr, nullptr, ca_q, CF_RELU};
        k_convm2<<<dim3(4,16,16), 256, 0, stream>>>(aj, 1.f);
    }

    // ================= PIXEL =================
    if (paired_pixel){
        ConvJobs qkvj = {};
        qkvj.j[0] = {sa_s, nullptr, pqw, pqb, nullptr, nullptr, nullptr, B[4],  CF_SPLIT|CF_TRANS};
        qkvj.j[1] = {ca_q, nullptr, pkw, pkb, nullptr, nullptr, nullptr, B[5],  CF_SPLIT|CF_TRANS};
        qkvj.j[2] = {ca_q, nullptr, pvw, pvb, nullptr, nullptr, nullptr, B[6],  CF_SPLIT};
        qkvj.j[3] = {sa_q, nullptr, pqw, pqb, nullptr, nullptr, nullptr, B[8],  CF_SPLIT|CF_TRANS};
        qkvj.j[4] = {ca_s, nullptr, pkw, pkb, nullptr, nullptr, nullptr, B[9],  CF_SPLIT|CF_TRANS};
        qkvj.j[5] = {ca_s, nullptr, pvw, pvb, nullptr, nullptr, nullptr, B[10], CF_SPLIT};
        k_convm<<<dim3(4,8,48), 512, 0, stream>>>(qkvj, 1.f);
        if (!has_dsplit){
            ZJobs zj = {{B[7], B[11]}};
            k_zero<<<dim3(4096,2), 256, 0, stream>>>(zj);
        }
        float* o2a = has_dsplit ? B[12] : nullptr;
        float* o2b = has_dsplit ? B[13] : nullptr;
        PixJobs pxj = {{{(const unsigned*)B[4], (const unsigned*)B[5], (const unsigned*)B[6],  B[7],  o2a},
                        {(const unsigned*)B[8], (const unsigned*)B[9], (const unsigned*)B[10], B[11], o2b}}};
        k_pixel_mfma<<<dim3(8,16,8), 256, 0, stream>>>(pxj);
        ConvJobs ppj = {};
        ppj.j[0] = {B[7],  o2a, ppw, ppb, sa_s, nullptr, nullptr, out0, CF_RES};
        ppj.j[1] = {B[11], o2b, ppw, ppb, sa_q, nullptr, nullptr, out1, CF_RES};
        k_convm2<<<dim3(4,16,16), 256, 0, stream>>>(ppj, 1.f);
        LnJobs lj = {{out0, out1}, {B[4], B[8]}};
        k_ln_pix<<<dim3(2048,2), 64, 0, stream>>>(lj, plng, plnb);
        ConvJobs lnj = {};
        lnj.j[0] = {B[4], nullptr, plinw, plinb, nullptr, nullptr, nullptr, out0, CF_RELU};
        lnj.j[1] = {B[8], nullptr, plinw, plinb, nullptr, nullptr, nullptr, out1, CF_RELU};
        k_convm2<<<dim3(4,16,16), 256, 0, stream>>>(lnj, 1.f);
    } else {
        auto pixel1 = [&](const float* x1, const float* x2, float* out){
            ConvJobs qkvj = {};
            qkvj.j[0] = {x1, nullptr, pqw, pqb, nullptr, nullptr, nullptr, B[4], CF_SPLIT|CF_TRANS};
            qkvj.j[1] = {x2, nullptr, pkw, pkb, nullptr, nullptr, nullptr, B[5], CF_SPLIT|CF_TRANS};
            qkvj.j[2] = {x2, nullptr, pvw, pvb, nullptr, nullptr, nullptr, B[6], CF_SPLIT};
            k_convm<<<dim3(4,8,24), 512, 0, stream>>>(qkvj, 1.f);
            ZJobs zj = {{B[7], B[7]}};
            k_zero<<<dim3(4096,1), 256, 0, stream>>>(zj);
            PixJobs pxj = {{{(const unsigned*)B[4], (const unsigned*)B[5], (const unsigned*)B[6], B[7], nullptr},
                            {(const unsigned*)B[4], (const unsigned*)B[5], (const unsigned*)B[6], B[7], nullptr}}};
            k_pixel_mfma<<<dim3(8,8,8), 256, 0, stream>>>(pxj);
            ConvJobs ppj = {};
            ppj.j[0] = {B[7], nullptr, ppw, ppb, x1, nullptr, nullptr, out, CF_RES};
            k_convm2<<<dim3(4,16,8), 256, 0, stream>>>(ppj, 1.f);
            LnJobs lj = {{out, out}, {B[4], B[4]}};
            k_ln_pix<<<dim3(2048,1), 64, 0, stream>>>(lj, plng, plnb);
            ConvJobs lnj = {};
            lnj.j[0] = {B[4], nullptr, plinw, plinb, nullptr, nullptr, nullptr, out, CF_RELU};
            k_convm2<<<dim3(4,16,8), 256, 0, stream>>>(lnj, 1.f);
        };
        pixel1(sa_s, ca_q, out0);
        pixel1(sa_q, ca_s, out1);
    }

    (void)in_sizes; (void)n_in; (void)out_size;
}

// Round 12
// 473.168 us; speedup vs baseline: 1.0467x; 1.0467x over previous
//
#include <hip/hip_runtime.h>
#include <cmath>

// ---------- constants ----------
#define IMG 131072        // 512*256 per batch image (elements; also u32/batch for packed planes)
#define BIGF 1048576      // 8*512*256

#define CF_RELU  1
#define CF_RES   2
#define CF_BN    4
#define CF_SPLIT 8
#define CF_TRANS 16

typedef __attribute__((ext_vector_type(8))) short short8;
typedef __attribute__((ext_vector_type(4))) short short4v;
typedef __attribute__((ext_vector_type(4))) float f32x4;

__device__ __forceinline__ float wave_sum(float v){
    #pragma unroll
    for (int off = 32; off; off >>= 1) v += __shfl_xor(v, off);
    return v;
}

__device__ __forceinline__ unsigned short bf16_rn(float x){
    union { float f; unsigned u; } v; v.f = x;
    unsigned r = v.u + 0x7FFF + ((v.u >> 16) & 1);
    return (unsigned short)(r >> 16);
}
__device__ __forceinline__ float bf16_to_f(unsigned short h){
    union { float f; unsigned u; } v; v.u = ((unsigned)h) << 16;
    return v.f;
}
__device__ __forceinline__ unsigned pack_split(float x){
    unsigned short hi = bf16_rn(x);
    unsigned short lo = bf16_rn(x - bf16_to_f(hi));
    return (unsigned)hi | ((unsigned)lo << 16);
}
// pack low16/high16 halves of two packed (hi|lo<<16) words:
// pk_hi(a,b) = {a.lo16, b.lo16}   pk_lo(a,b) = {a.hi16, b.hi16}
__device__ __forceinline__ unsigned pk_hi(unsigned a, unsigned b){
    return __builtin_amdgcn_perm(b, a, 0x05040100u);
}
__device__ __forceinline__ unsigned pk_lo(unsigned a, unsigned b){
    return __builtin_amdgcn_perm(b, a, 0x07060302u);
}

// ---------- job structs (paired launches across the two branches) ----------
struct GapJobs  { const float* x[2]; float* o[2]; };
struct G8Job    { const float* in; const float* W; const float* bias; const float* add; float* out; };
struct G8Jobs   { G8Job j[4]; };
struct AAJobs   { const float* qkv[2]; float* om[2]; };
struct LnJobs   { const float* in[2]; float* out[2]; };
struct UpJobs   { const float* in[2]; float* out[2]; };
struct SAJobs   { const float* q8[2]; const float* k8[2]; float* aw[2]; };
struct SPJobs   { const float* aw[2]; const float* v[2]; float* out[2]; };
struct ZJobs    { float* p[2]; };
struct ConvJob  { const float* X; const float* X2; const float* W; const float* B; const float* R;
                  const float* bng; const float* bnb; float* O; int flags; };
struct ConvJobs { ConvJob j[6]; };
struct PixJob   { const unsigned* Q; const unsigned* K; const unsigned* V; float* Oa; float* Ob; };
struct PixJobs  { PixJob j[2]; };

// ---------- GAP: mean over 256 spatial ----------
__global__ __launch_bounds__(64) void k_gap(GapJobs jo){
    const int br = blockIdx.y;
    const int bc = blockIdx.x;           // b*512 + c
    const int lane = threadIdx.x;
    const float* p = jo.x[br] + (size_t)bc * 256;
    float s = p[lane] + p[lane + 64] + p[lane + 128] + p[lane + 192];
    s = wave_sum(s);
    if (lane == 0) jo.o[br][bc] = s * (1.0f / 256.0f);
}

// ---------- tiny GEMM: out[8,O] = in[8,512] @ W[O,512]^T + bias (+add) ----------
__global__ __launch_bounds__(64) void k_gemm8(G8Jobs jo, int add_off, int add_stride, int O, int relu){
    const G8Job j = jo.j[blockIdx.y];
    const int o = blockIdx.x;
    const int lane = threadIdx.x;
    const float* wr = j.W + (size_t)o * 512;
    float acc[8] = {0,0,0,0,0,0,0,0};
    #pragma unroll
    for (int i = 0; i < 8; i++){
        float w = wr[lane + 64*i];
        #pragma unroll
        for (int b = 0; b < 8; b++) acc[b] += w * j.in[b*512 + lane + 64*i];
    }
    #pragma unroll
    for (int b = 0; b < 8; b++) acc[b] = wave_sum(acc[b]);
    if (lane < 8){
        float v = acc[0];
        #pragma unroll
        for (int b = 1; b < 8; b++) if (lane == b) v = acc[b];
        v += j.bias[o];
        if (j.add) v += j.add[lane*add_stride + add_off + o];
        if (relu) v = fmaxf(v, 0.f);
        j.out[(size_t)lane * O + o] = v;
    }
}

// ---------- asri batch-axis attention; writes merged o [8,512] ----------
__global__ __launch_bounds__(64) void k_asri_attn(AAJobs jo){
    const int br = blockIdx.y;
    const float* qkv = jo.qkv[br];
    const int h = blockIdx.x >> 3, b = blockIdx.x & 7, c = threadIdx.x;
    const int ci = c*8 + h;
    float qc = qkv[b*2048 + ci];
    float s[8];
    #pragma unroll
    for (int d = 0; d < 8; d++){
        float p = qc * qkv[d*2048 + 512 + ci];
        p = wave_sum(p);
        s[d] = p * 0.125f;
    }
    float m = s[0];
    #pragma unroll
    for (int d = 1; d < 8; d++) m = fmaxf(m, s[d]);
    float sum = 0.f;
    #pragma unroll
    for (int d = 0; d < 8; d++){ s[d] = __expf(s[d]-m); sum += s[d]; }
    float r = 1.f / sum;
    float oc = 0.f;
    #pragma unroll
    for (int d = 0; d < 8; d++) oc += s[d]*r * qkv[d*2048 + 1024 + ci];
    jo.om[br][b*512 + ci] = oc;
}

// ---------- LN over 512, 8 rows ----------
__global__ __launch_bounds__(64) void k_ln8(LnJobs jo,
    const float* __restrict__ g, const float* __restrict__ be)
{
    const int br = blockIdx.y;
    const int b = blockIdx.x, lane = threadIdx.x;
    const float* in = jo.in[br];
    float v[8]; float s = 0.f;
    #pragma unroll
    for (int i = 0; i < 8; i++){ v[i] = in[b*512 + lane + 64*i]; s += v[i]; }
    s = wave_sum(s);
    float mean = s * (1.f/512.f);
    float q = 0.f;
    #pragma unroll
    for (int i = 0; i < 8; i++){ float d = v[i]-mean; q += d*d; }
    q = wave_sum(q);
    float rstd = rsqrtf(q*(1.f/512.f) + 1e-5f);
    #pragma unroll
    for (int i = 0; i < 8; i++){
        int c = lane + 64*i;
        jo.out[br][b*512 + c] = (v[i]-mean)*rstd*g[c] + be[c];
    }
}

// ---------- bilinear upsample 4x4 -> 16x16 align_corners ----------
__global__ __launch_bounds__(256) void k_up(UpJobs jo){
    const int br = blockIdx.y;
    const int idx = blockIdx.x*256 + threadIdx.x;
    const int x = idx & 15, y = (idx >> 4) & 15, bc = idx >> 8;
    float px = (float)(x*3) / 15.0f, py = (float)(y*3) / 15.0f;
    int lx = (int)px, ly = (int)py;
    float wx = px - lx, wy = py - ly;
    int hx = min(lx+1, 3), hy = min(ly+1, 3);
    const float* p = jo.in[br] + (size_t)bc * 16;
    float v00 = p[ly*4+lx], v01 = p[ly*4+hx], v10 = p[hy*4+lx], v11 = p[hy*4+hx];
    float a0 = v00*(1.f-wy) + v10*wy;
    float a1 = v01*(1.f-wy) + v11*wy;
    jo.out[br][idx] = a0*(1.f-wx) + a1*wx;
}

// ---------- zero fill (fallback path only) ----------
__global__ __launch_bounds__(256) void k_zero(ZJobs jo){
    jo.p[blockIdx.y][(size_t)blockIdx.x*256 + threadIdx.x] = 0.f;
}

// ---------- conv1x1 via split-bf16 MFMA: 512 thr, K-split across 2 wave-groups ----------
// CF_SPLIT: epilogue writes packed split-bf16 (hi | lo<<16) u32 per element, layout [c][n].
// CF_SPLIT|CF_TRANS: transposed head-grouped layout [n][p], p = h*64+i (o = i*8+h), via
//   weight-row permutation + MFMA operand swap (coalesced stores; bit-identical products).
// X2: optional second input plane summed during staging (pixel d-group partials).
#define LDK 40
__device__ __forceinline__ void convm_body(
    const float* __restrict__ Xb, const float* __restrict__ X2b,
    const float* __restrict__ W,
    const float* __restrict__ bias, const float* __restrict__ resb,
    const float* __restrict__ bng, const float* __restrict__ bnb, float bninv,
    float* __restrict__ outb, int flags, int o0, int n0, unsigned short* lds)
{
    const int tid512 = threadIdx.x;
    const int g   = tid512 >> 8;          // K-group
    const int tid = tid512 & 255;
    unsigned short* sAh = lds + g*10240;
    unsigned short* sAl = sAh + 2560;
    unsigned short* sBh = sAl + 2560;
    unsigned short* sBl = sBh + 2560;
    const int wv = tid >> 6, lane = tid & 63;
    const int quad = lane >> 4, l16 = lane & 15;
    const int wo = (wv >> 1) * 32, wn = (wv & 1) * 32;
    const int so  = tid >> 2, sk8 = (tid & 3) * 8;
    const int sp  = tid & 15, sn  = (tid >> 4) * 4;

    const bool trans = (flags & CF_TRANS) != 0;
    int so_g = o0 + so;
    if (trans) so_g = ((so_g & 63) << 3) | (so_g >> 6);   // load W row for output position p

    const float* wrow = W + (size_t)so_g*512 + g*256 + sk8;
    const size_t xoff = (size_t)(g*256 + 2*sp)*256 + n0 + sn;
    const float* xrow  = Xb + xoff;
    const float* x2row = X2b ? X2b + xoff : nullptr;

    auto ldx4 = [&](size_t off){
        float4 v = *(const float4*)(xrow + off);
        if (x2row){
            float4 w2 = *(const float4*)(x2row + off);
            v.x += w2.x; v.y += w2.y; v.z += w2.z; v.w += w2.w;
        }
        return v;
    };

    f32x4 acc[2][2] = {};
    float4 a0 = *(const float4*)(wrow);
    float4 a1 = *(const float4*)(wrow + 4);
    float4 x0 = ldx4(0);
    float4 x1 = ldx4(256);

    for (int k0 = 0; k0 < 256; k0 += 32){
        __syncthreads();
        {
            float wa[8] = {a0.x,a0.y,a0.z,a0.w,a1.x,a1.y,a1.z,a1.w};
            #pragma unroll
            for (int j = 0; j < 4; j++){
                unsigned short h0 = bf16_rn(wa[2*j]);
                unsigned short h1 = bf16_rn(wa[2*j+1]);
                unsigned short g0 = bf16_rn(wa[2*j]   - bf16_to_f(h0));
                unsigned short g1 = bf16_rn(wa[2*j+1] - bf16_to_f(h1));
                *(unsigned*)&sAh[so*LDK + sk8 + 2*j] = (unsigned)h0 | ((unsigned)h1 << 16);
                *(unsigned*)&sAl[so*LDK + sk8 + 2*j] = (unsigned)g0 | ((unsigned)g1 << 16);
            }
            float xe[4] = {x0.x,x0.y,x0.z,x0.w};
            float xo[4] = {x1.x,x1.y,x1.z,x1.w};
            #pragma unroll
            for (int j = 0; j < 4; j++){
                unsigned short h0 = bf16_rn(xe[j]);
                unsigned short h1 = bf16_rn(xo[j]);
                unsigned short g0 = bf16_rn(xe[j] - bf16_to_f(h0));
                unsigned short g1 = bf16_rn(xo[j] - bf16_to_f(h1));
                *(unsigned*)&sBh[(sn+j)*LDK + 2*sp] = (unsigned)h0 | ((unsigned)h1 << 16);
                *(unsigned*)&sBl[(sn+j)*LDK + 2*sp] = (unsigned)g0 | ((unsigned)g1 << 16);
            }
        }
        __syncthreads();
        if (k0 + 32 < 256){
            a0 = *(const float4*)(wrow + k0 + 32);
            a1 = *(const float4*)(wrow + k0 + 36);
            x0 = ldx4((size_t)(k0+32)*256);
            x1 = ldx4((size_t)(k0+32)*256 + 256);
        }
        short8 ah[2], al[2], bh[2], bl[2];
        #pragma unroll
        for (int t = 0; t < 2; t++){
            int ai = (wo + 16*t + l16)*LDK + quad*8;
            ah[t] = *(const short8*)&sAh[ai];
            al[t] = *(const short8*)&sAl[ai];
            int bi = (wn + 16*t + l16)*LDK + quad*8;
            bh[t] = *(const short8*)&sBh[bi];
            bl[t] = *(const short8*)&sBl[bi];
        }
        if (trans){
            #pragma unroll
            for (int mt = 0; mt < 2; mt++){
                #pragma unroll
                for (int nt = 0; nt < 2; nt++){
                    acc[mt][nt] = __builtin_amdgcn_mfma_f32_16x16x32_bf16(bh[nt], ah[mt], acc[mt][nt], 0, 0, 0);
                    acc[mt][nt] = __builtin_amdgcn_mfma_f32_16x16x32_bf16(bl[nt], ah[mt], acc[mt][nt], 0, 0, 0);
                    acc[mt][nt] = __builtin_amdgcn_mfma_f32_16x16x32_bf16(bh[nt], al[mt], acc[mt][nt], 0, 0, 0);
                }
            }
        } else {
            #pragma unroll
            for (int mt = 0; mt < 2; mt++){
                #pragma unroll
                for (int nt = 0; nt < 2; nt++){
                    acc[mt][nt] = __builtin_amdgcn_mfma_f32_16x16x32_bf16(ah[mt], bh[nt], acc[mt][nt], 0, 0, 0);
                    acc[mt][nt] = __builtin_amdgcn_mfma_f32_16x16x32_bf16(ah[mt], bl[nt], acc[mt][nt], 0, 0, 0);
                    acc[mt][nt] = __builtin_amdgcn_mfma_f32_16x16x32_bf16(al[mt], bh[nt], acc[mt][nt], 0, 0, 0);
                }
            }
        }
    }
    // ---- cross-group reduction (stride-20 float rows: conflict-benign) ----
    __syncthreads();
    float* red = (float*)lds;
    if (g == 1){
        float* r = red + tid*20;
        #pragma unroll
        for (int mt = 0; mt < 2; mt++)
            #pragma unroll
            for (int nt = 0; nt < 2; nt++)
                *(f32x4*)(r + (mt*2+nt)*4) = acc[mt][nt];
    }
    __syncthreads();
    if (g == 0){
        float* r = red + tid*20;
        #pragma unroll
        for (int mt = 0; mt < 2; mt++)
            #pragma unroll
            for (int nt = 0; nt < 2; nt++){
                f32x4 o4 = *(const f32x4*)(r + (mt*2+nt)*4);
                acc[mt][nt] += o4;
            }
        if (trans){
            // rows = n (X free dim), cols = p (permuted W free dim) -> coalesced u32 stores
            unsigned* op = (unsigned*)outb;
            #pragma unroll
            for (int mt = 0; mt < 2; mt++){
                #pragma unroll
                for (int nt = 0; nt < 2; nt++){
                    const int p  = o0 + wo + 16*mt + l16;
                    const int nb = n0 + wn + 16*nt + quad*4;
                    const int osrc = ((p & 63) << 3) | (p >> 6);
                    const float bs = bias[osrc];
                    #pragma unroll
                    for (int rr = 0; rr < 4; rr++){
                        float v = acc[mt][nt][rr] + bs;
                        op[(size_t)(nb+rr)*512 + p] = pack_split(v);
                    }
                }
            }
        } else {
            #pragma unroll
            for (int mt = 0; mt < 2; mt++){
                #pragma unroll
                for (int nt = 0; nt < 2; nt++){
                    const int n  = n0 + wn + 16*nt + l16;
                    const int ob = o0 + wo + 16*mt + quad*4;
                    #pragma unroll
                    for (int rr = 0; rr < 4; rr++){
                        const int o = ob + rr;
                        float v = acc[mt][nt][rr] + bias[o];
                        if (flags & CF_BN)   v = v*(bninv*bng[o]) + bnb[o];
                        if (flags & CF_RELU) v = fmaxf(v, 0.f);
                        if (flags & CF_RES)  v += resb[(size_t)o*256 + n];
                        if (flags & CF_SPLIT){
                            ((unsigned*)outb)[(size_t)o*256 + n] = pack_split(v);
                        } else {
                            outb[(size_t)o*256 + n] = v;
                        }
                    }
                }
            }
        }
    }
}

__global__ __launch_bounds__(512) void k_convm(ConvJobs jo, float bninv)
{
    __shared__ unsigned short lds[20480];   // 40 KB: 2 groups x 4 planes x 64x40
    const int z = blockIdx.z;
    const ConvJob j = jo.j[z >> 3];
    const int b = z & 7;
    convm_body(j.X + (size_t)b*IMG,
               j.X2 ? j.X2 + (size_t)b*IMG : nullptr,
               j.W, j.B,
               j.R ? j.R + (size_t)b*IMG : nullptr,
               j.bng, j.bnb, bninv,
               j.O + (size_t)b*IMG, j.flags,
               blockIdx.y*64, blockIdx.x*64, lds);
}

// ---------- sscm attention weights [h][b][d] ----------
__global__ __launch_bounds__(64) void k_sscm_attn(SAJobs jo)
{
    const int br = blockIdx.y;
    const int h = blockIdx.x >> 3, b = blockIdx.x & 7, c = threadIdx.x;
    const int ci = c*8 + h;
    float qc = jo.q8[br][b*512 + ci];
    float s[8];
    #pragma unroll
    for (int d = 0; d < 8; d++){
        float p = qc * jo.k8[br][d*512 + ci];
        p = wave_sum(p);
        s[d] = p * 0.125f;
    }
    float m = s[0];
    #pragma unroll
    for (int d = 1; d < 8; d++) m = fmaxf(m, s[d]);
    float sum = 0.f;
    #pragma unroll
    for (int d = 0; d < 8; d++){ s[d] = __expf(s[d]-m); sum += s[d]; }
    float r = 1.f/sum;
    if (c < 8){
        float v = s[0];
        #pragma unroll
        for (int d = 1; d < 8; d++) if (c == d) v = s[d];
        jo.aw[br][blockIdx.x*8 + c] = v*r;
    }
}

// ---------- sscm apply ----------
__global__ __launch_bounds__(256) void k_sscm_apply(SPJobs jo)
{
    const int br = blockIdx.y;
    const int idx = blockIdx.x*256 + threadIdx.x;
    const int pix = idx & 255, e = (idx >> 8) & 511, b = idx >> 17;
    const int h = e & 7;
    const float* aw = jo.aw[br] + (h*8 + b)*8;
    const float* v = jo.v[br];
    float acc = 0.f;
    #pragma unroll
    for (int d = 0; d < 8; d++) acc += aw[d] * v[(size_t)d*IMG + (size_t)e*256 + pix];
    jo.out[br][idx] = acc;
}

// ---------- pixel cross-batch attention, v7 (round-7 proven: T14 async-STAGE + setprio) ----------
__global__ __launch_bounds__(256) void k_pixel_mfma(PixJobs jo)
{
    __shared__ char smem[40960];
    unsigned short* sQh = (unsigned short*)smem;      // [2 ks][64 q][40]      5120 ush
    unsigned short* sQl = sQh + 2*64*40;              //                       5120
    unsigned short* sKh = sQl + 2*64*40;              // [2 chan-ks][64 m][40] 5120
    unsigned short* sKl = sKh + 2*64*40;              //                       5120
    unsigned short* sP  = (unsigned short*)smem;      // [4 mks][64 q][40] aliases Q region
    unsigned short* sVh = sKh;                        // [2 mks][64 c][40] aliases K region
    unsigned short* sVl = sKl;

    const int br = blockIdx.y >> 3, b = blockIdx.y & 7;
    const PixJob J = jo.j[br];
    const int nt = blockIdx.x & 3, dg = blockIdx.x >> 2;
    const int h = blockIdx.z;
    const int tid = threadIdx.x;
    const int wv = tid >> 6, lane = tid & 63;
    const int quad = lane >> 4, l16 = lane & 15;
    const int n0 = nt * 64;

    // ---- stage Q once: [n0+q][h*64 + i], channel-contiguous vector loads ----
    {
        const unsigned* Qt = J.Q + (size_t)b*IMG + (size_t)n0*512 + h*64;
        const int q = tid >> 2, i0 = (tid & 3) * 16;
        const unsigned* src = Qt + (size_t)q*512 + i0;
        uint4 w0 = *(const uint4*)(src);
        uint4 w1 = *(const uint4*)(src + 4);
        uint4 w2 = *(const uint4*)(src + 8);
        uint4 w3 = *(const uint4*)(src + 12);
        unsigned hb[8], lb[8];
        hb[0]=pk_hi(w0.x,w0.y); hb[1]=pk_hi(w0.z,w0.w); hb[2]=pk_hi(w1.x,w1.y); hb[3]=pk_hi(w1.z,w1.w);
        hb[4]=pk_hi(w2.x,w2.y); hb[5]=pk_hi(w2.z,w2.w); hb[6]=pk_hi(w3.x,w3.y); hb[7]=pk_hi(w3.z,w3.w);
        lb[0]=pk_lo(w0.x,w0.y); lb[1]=pk_lo(w0.z,w0.w); lb[2]=pk_lo(w1.x,w1.y); lb[3]=pk_lo(w1.z,w1.w);
        lb[4]=pk_lo(w2.x,w2.y); lb[5]=pk_lo(w2.z,w2.w); lb[6]=pk_lo(w3.x,w3.y); lb[7]=pk_lo(w3.z,w3.w);
        int dst = (i0>>5)*2560 + q*40 + (i0&31);
        *(uint4*)&sQh[dst]     = *(uint4*)&hb[0];
        *(uint4*)&sQh[dst + 8] = *(uint4*)&hb[4];
        *(uint4*)&sQl[dst]     = *(uint4*)&lb[0];
        *(uint4*)&sQl[dst + 8] = *(uint4*)&lb[4];
    }
    __syncthreads();

    short8 bqh[2], bql[2];
    #pragma unroll
    for (int ks = 0; ks < 2; ks++){
        int idx = ks*2560 + (wv*16 + l16)*40 + quad*8;
        bqh[ks] = *(const short8*)&sQh[idx];
        bql[ks] = *(const short8*)&sQl[idx];
    }

    // ---- prefetch machinery: one 16-VGPR buffer, time-shared K/V ----
    const int mloc = tid & 63, cb0 = tid >> 6;   // K staging coords
    const int mp = tid & 31,  c0v = tid >> 5;    // V staging coords
    uint4 pf[4];

    auto loadK = [&](int d, int mq){
        const unsigned* Kt = J.K + (size_t)d*IMG + (size_t)(mq*64 + mloc)*512 + h*64;
        pf[0] = *(const uint4*)(Kt + cb0*8);
        pf[1] = *(const uint4*)(Kt + cb0*8 + 4);
        pf[2] = *(const uint4*)(Kt + (cb0+4)*8);
        pf[3] = *(const uint4*)(Kt + (cb0+4)*8 + 4);
    };
    auto writeK = [&](){
        #pragma unroll
        for (int p = 0; p < 2; p++){
            uint4 wa = pf[2*p], wb = pf[2*p+1];
            union { short8 s; unsigned u[4]; } hu, lu;
            hu.u[0]=pk_hi(wa.x,wa.y); hu.u[1]=pk_hi(wa.z,wa.w);
            hu.u[2]=pk_hi(wb.x,wb.y); hu.u[3]=pk_hi(wb.z,wb.w);
            lu.u[0]=pk_lo(wa.x,wa.y); lu.u[1]=pk_lo(wa.z,wa.w);
            lu.u[2]=pk_lo(wb.x,wb.y); lu.u[3]=pk_lo(wb.z,wb.w);
            int cb = cb0 + 4*p;
            int idx = (cb>>2)*2560 + mloc*40 + (cb&3)*8;
            *(short8*)&sKh[idx] = hu.s;
            *(short8*)&sKl[idx] = lu.s;
        }
    };
    auto loadV = [&](int d, int vs){
        const unsigned* Vp = J.V + (size_t)d*IMG + (size_t)h*256 + (vs>>1)*128 + (vs&1)*64 + 2*mp;
        #pragma unroll
        for (int p2 = 0; p2 < 4; p2++){
            uint2 wA = *(const uint2*)(Vp + (size_t)(c0v + 16*p2)*2048);
            uint2 wB = *(const uint2*)(Vp + (size_t)(c0v + 16*p2 + 8)*2048);
            pf[p2].x = wA.x; pf[p2].y = wA.y; pf[p2].z = wB.x; pf[p2].w = wB.y;
        }
    };
    auto writeV = [&](){
        const int ib = ((2*mp)>>5)*2560 + ((2*mp)&31);
        #pragma unroll
        for (int p2 = 0; p2 < 4; p2++){
            int ca = c0v + 16*p2, cb2 = ca + 8;
            *(unsigned*)&sVh[ib + ca*40]  = pk_hi(pf[p2].x, pf[p2].y);
            *(unsigned*)&sVl[ib + ca*40]  = pk_lo(pf[p2].x, pf[p2].y);
            *(unsigned*)&sVh[ib + cb2*40] = pk_hi(pf[p2].z, pf[p2].w);
            *(unsigned*)&sVl[ib + cb2*40] = pk_lo(pf[p2].z, pf[p2].w);
        }
    };

    f32x4 oac[4] = {};
    loadK(dg*4, 0);   // prime the pipeline

    for (int dd = 0; dd < 4; dd++){
        const int d = dg*4 + dd;

        // ---- S = Q @ K^T, 4 m-quarters; K prefetched one phase ahead ----
        f32x4 S[16] = {};
        #pragma unroll
        for (int mq = 0; mq < 4; mq++){
            if (mq | dd) __syncthreads();   // prior sK(S)/sV(PV) reads done
            writeK();
            if (mq < 3) loadK(d, mq+1);     // in flight during barrier+MFMA below
            else        loadV(d, 0);        // V(vs=0) hidden under last MFMA + softmax
            __syncthreads();
            __builtin_amdgcn_s_setprio(1);
            #pragma unroll
            for (int mtl = 0; mtl < 4; mtl++){
                int t = mq*4 + mtl;
                #pragma unroll
                for (int ks = 0; ks < 2; ks++){
                    int idx = ks*2560 + (mtl*16 + l16)*40 + quad*8;
                    short8 ah = *(const short8*)&sKh[idx];
                    short8 al = *(const short8*)&sKl[idx];
                    S[t] = __builtin_amdgcn_mfma_f32_16x16x32_bf16(ah, bqh[ks], S[t], 0, 0, 0);
                    S[t] = __builtin_amdgcn_mfma_f32_16x16x32_bf16(ah, bql[ks], S[t], 0, 0, 0);
                    S[t] = __builtin_amdgcn_mfma_f32_16x16x32_bf16(al, bqh[ks], S[t], 0, 0, 0);
                }
            }
            __builtin_amdgcn_s_setprio(0);
        }

        // ---- softmax over this key batch's 256 m (exact, per reference) ----
        {
            float mx = -3.4e38f;
            #pragma unroll
            for (int t = 0; t < 16; t++)
                #pragma unroll
                for (int r = 0; r < 4; r++) mx = fmaxf(mx, S[t][r]);
            mx = fmaxf(mx, __shfl_xor(mx, 16));
            mx = fmaxf(mx, __shfl_xor(mx, 32));
            float sum = 0.f;
            #pragma unroll
            for (int t = 0; t < 16; t++)
                #pragma unroll
                for (int r = 0; r < 4; r++){ S[t][r] = __expf(S[t][r]-mx); sum += S[t][r]; }
            sum += __shfl_xor(sum, 16);
            sum += __shfl_xor(sum, 32);
            float rr = 1.f/sum;
            #pragma unroll
            for (int t = 0; t < 16; t++)
                #pragma unroll
                for (int r = 0; r < 4; r++) S[t][r] *= rr;
        }

        // ---- O += P @ V, vs-linear (hm=vs>>1, sub=vs&1); V prefetched one phase ahead ----
        #pragma unroll
        for (int vs = 0; vs < 4; vs++){
            __syncthreads();   // prior sK(S last mq)/sP/sV reads done
            if ((vs & 1) == 0){
                const int hm = vs >> 1;
                #pragma unroll
                for (int mtl = 0; mtl < 8; mtl++){
                    int t = hm*8 + mtl;
                    short4v p4;
                    #pragma unroll
                    for (int r = 0; r < 4; r++) p4[r] = (short)bf16_rn(S[t][r]);
                    int idx = (mtl>>1)*2560 + (wv*16 + l16)*40 + 16*(mtl&1) + quad*4;
                    *(short4v*)&sP[idx] = p4;
                }
            }
            writeV();
            if (vs < 3)      loadV(d, vs+1);      // in flight during barrier+MFMA below
            else if (dd < 3) loadK(d+1, 0);       // next key batch's first K quarter
            __syncthreads();
            __builtin_amdgcn_s_setprio(1);
            #pragma unroll
            for (int l = 0; l < 2; l++){
                int gks = (vs & 1)*2 + l;
                int pidx = gks*2560 + (wv*16 + l16)*40 + quad*8;
                short8 bp = *(const short8*)&sP[pidx];
                #pragma unroll
                for (int ct = 0; ct < 4; ct++){
                    int vidx = l*2560 + (ct*16 + l16)*40 + quad*8;
                    short8 vh = *(const short8*)&sVh[vidx];
                    short8 vl = *(const short8*)&sVl[vidx];
                    oac[ct] = __builtin_amdgcn_mfma_f32_16x16x32_bf16(vh, bp, oac[ct], 0, 0, 0);
                    oac[ct] = __builtin_amdgcn_mfma_f32_16x16x32_bf16(vl, bp, oac[ct], 0, 0, 0);
                }
            }
            __builtin_amdgcn_s_setprio(0);
        }
    }

    // ---- single output: plain store to this d-group's partial buffer ----
    {
        float* base = (J.Ob ? (dg ? J.Ob : J.Oa) : J.Oa);
        float* Obp = base + (size_t)b * IMG;
        const int q = n0 + wv*16 + l16;
        if (J.Ob){
            #pragma unroll
            for (int ct = 0; ct < 4; ct++){
                #pragma unroll
                for (int r = 0; r < 4; r++){
                    int c = ct*16 + quad*4 + r;
                    Obp[(size_t)(c*8+h)*256 + q] = oac[ct][r];
                }
            }
        } else {
            #pragma unroll
            for (int ct = 0; ct < 4; ct++){
                #pragma unroll
                for (int r = 0; r < 4; r++){
                    int c = ct*16 + quad*4 + r;
                    unsafeAtomicAdd(&Obp[(size_t)(c*8+h)*256 + q], oac[ct][r]);
                }
            }
        }
    }
}

// ---------- LN over channels (strided), keeps [b][c][n] layout ----------
__global__ __launch_bounds__(64) void k_ln_pix(LnJobs jo,
    const float* __restrict__ g, const float* __restrict__ be)
{
    const int br = blockIdx.y;
    const int bn = blockIdx.x;
    const int b = bn >> 8, n = bn & 255;
    const int lane = threadIdx.x;
    const float* p = jo.in[br] + (size_t)b*IMG + n;
    float v[8]; float s = 0.f;
    #pragma unroll
    for (int i = 0; i < 8; i++){ v[i] = p[(size_t)(lane + 64*i)*256]; s += v[i]; }
    s = wave_sum(s);
    float mean = s * (1.f/512.f);
    float q = 0.f;
    #pragma unroll
    for (int i = 0; i < 8; i++){ float d = v[i]-mean; q += d*d; }
    q = wave_sum(q);
    float rstd = rsqrtf(q*(1.f/512.f) + 1e-5f);
    #pragma unroll
    for (int i = 0; i < 8; i++){
        int c = lane + 64*i;
        jo.out[br][(size_t)b*IMG + (size_t)c*256 + n] = (v[i]-mean)*rstd*g[c] + be[c];
    }
}

// ---------- host orchestration ----------
extern "C" void kernel_launch(void* const* d_in, const int* in_sizes, int n_in,
                              void* d_out, int out_size, void* d_ws, size_t ws_size,
                              hipStream_t stream)
{
    const float* xs    = (const float*)d_in[0];
    const float* xq    = (const float*)d_in[1];
    const float* qkvw  = (const float*)d_in[2];  const float* qkvb = (const float*)d_in[3];
    const float* paw   = (const float*)d_in[4];  const float* pab  = (const float*)d_in[5];
    const float* ln1g  = (const float*)d_in[6];  const float* ln1b = (const float*)d_in[7];
    const float* f1w   = (const float*)d_in[8];  const float* f1b  = (const float*)d_in[9];
    const float* f2w   = (const float*)d_in[10]; const float* f2b  = (const float*)d_in[11];
    const float* ln2g  = (const float*)d_in[12]; const float* ln2b = (const float*)d_in[13];
    const float* c1w   = (const float*)d_in[14]; const float* c1b  = (const float*)d_in[15];
    const float* c2w   = (const float*)d_in[16]; const float* c2b  = (const float*)d_in[17];
    const float* bng   = (const float*)d_in[18]; const float* bnb  = (const float*)d_in[19];
    const float* caqw  = (const float*)d_in[20]; const float* caqb = (const float*)d_in[21];
    const float* cakw  = (const float*)d_in[22]; const float* cakb = (const float*)d_in[23];
    const float* cavw  = (const float*)d_in[24]; const float* cavb = (const float*)d_in[25];
    const float* capw  = (const float*)d_in[26]; const float* capb = (const float*)d_in[27];
    const float* pqw   = (const float*)d_in[28]; const float* pqb  = (const float*)d_in[29];
    const float* pkw   = (const float*)d_in[30]; const float* pkb  = (const float*)d_in[31];
    const float* pvw   = (const float*)d_in[32]; const float* pvb  = (const float*)d_in[33];
    const float* ppw   = (const float*)d_in[34]; const float* ppb  = (const float*)d_in[35];
    const float* plng  = (const float*)d_in[36]; const float* plnb = (const float*)d_in[37];
    const float* plinw = (const float*)d_in[38]; const float* plinb= (const float*)d_in[39];

    const size_t SMF = 262144;  // small-scratch floats (2 branch regions of 131072)
    float* ws = (float*)d_ws;
    float* smb = ws;
    float* B[14];
    for (int i = 0; i < 14; i++) B[i] = ws + SMF + (size_t)i*BIGF;
    float* sa_s = B[0]; float* sa_q = B[1];
    float* ca_s = B[2]; float* ca_q = B[3];
    const bool paired_pixel = ws_size >= (SMF + 12*(size_t)BIGF)*sizeof(float) + 1024;
    const bool has_dsplit   = ws_size >= (SMF + 14*(size_t)BIGF)*sizeof(float) + 1024;

    auto SM = [&](int br){ return smb + (size_t)br*131072; };
    // per-branch small offsets
    auto GAP=[&](int br){ return SM(br); };            auto QKV=[&](int br){ return SM(br)+4096; };
    auto OM =[&](int br){ return SM(br)+20480; };      auto AA =[&](int br){ return SM(br)+24576; };
    auto HB =[&](int br){ return SM(br)+28672; };      auto A2 =[&](int br){ return SM(br)+32768; };
    auto LNB=[&](int br){ return SM(br)+36864; };      auto S8 =[&](int br){ return SM(br)+40960; };
    auto ATW=[&](int br){ return SM(br)+106496; };     auto Q8 =[&](int br){ return SM(br)+107008; };
    auto K8 =[&](int br){ return SM(br)+111104; };

    const float bninv = 1.0f / sqrtf(1.0f + 1e-5f);
    float* out0 = (float*)d_out;
    float* out1 = out0 + (size_t)BIGF;

    // ================= ASRI (both branches paired) =================
    {
        GapJobs gj = {{xs, xq}, {GAP(0), GAP(1)}};
        k_gap<<<dim3(4096,2), 64, 0, stream>>>(gj);
        G8Jobs qj = {{{GAP(0), qkvw, qkvb, nullptr, QKV(0)}, {GAP(1), qkvw, qkvb, nullptr, QKV(1)}}};
        k_gemm8<<<dim3(2048,2), 64, 0, stream>>>(qj, 0, 0, 2048, 0);
        AAJobs aj = {{QKV(0), QKV(1)}, {OM(0), OM(1)}};
        k_asri_attn<<<dim3(64,2), 64, 0, stream>>>(aj);
        G8Jobs pj = {{{OM(0), paw, pab, QKV(0), AA(0)}, {OM(1), paw, pab, QKV(1), AA(1)}}};
        k_gemm8<<<dim3(512,2), 64, 0, stream>>>(pj, 1536, 2048, 512, 0);
        LnJobs l1 = {{AA(0), AA(1)}, {LNB(0), LNB(1)}};
        k_ln8<<<dim3(8,2), 64, 0, stream>>>(l1, ln1g, ln1b);
        G8Jobs fj = {{{LNB(0), f1w, f1b, nullptr, HB(0)}, {LNB(1), f1w, f1b, nullptr, HB(1)}}};
        k_gemm8<<<dim3(512,2), 64, 0, stream>>>(fj, 0, 0, 512, 1);
        G8Jobs f2j = {{{HB(0), f2w, f2b, AA(0), A2(0)}, {HB(1), f2w, f2b, AA(1), A2(1)}}};
        k_gemm8<<<dim3(512,2), 64, 0, stream>>>(f2j, 0, 512, 512, 0);
        LnJobs l2 = {{A2(0), A2(1)}, {LNB(0), LNB(1)}};
        k_ln8<<<dim3(8,2), 64, 0, stream>>>(l2, ln2g, ln2b);
        G8Jobs cj = {{{LNB(0), c1w, c1b, nullptr, S8(0)}, {LNB(1), c1w, c1b, nullptr, S8(1)}}};
        k_gemm8<<<dim3(8192,2), 64, 0, stream>>>(cj, 0, 0, 8192, 0);
        UpJobs uj = {{S8(0), S8(1)}, {B[4], B[5]}};
        k_up<<<dim3(4096,2), 256, 0, stream>>>(uj);
        ConvJobs c2j = {};
        c2j.j[0] = {B[4], nullptr, c2w, c2b, xs, bng, bnb, sa_s, CF_BN|CF_RELU|CF_RES};
        c2j.j[1] = {B[5], nullptr, c2w, c2b, xq, bng, bnb, sa_q, CF_BN|CF_RELU|CF_RES};
        k_convm<<<dim3(4,8,16), 512, 0, stream>>>(c2j, bninv);
    }

    // ================= SSCM (both branches paired) =================
    {
        GapJobs gj = {{sa_s, sa_q}, {GAP(0), GAP(1)}};   // gap0 = gap(sa_s), gap1 = gap(sa_q)
        k_gap<<<dim3(4096,2), 64, 0, stream>>>(gj);
        G8Jobs qj = {{{GAP(0), caqw, caqb, nullptr, Q8(0)},   // br0: q from sa_s
                      {GAP(1), cakw, cakb, nullptr, K8(0)},   // br0: k from sa_q
                      {GAP(1), caqw, caqb, nullptr, Q8(1)},   // br1: q from sa_q
                      {GAP(0), cakw, cakb, nullptr, K8(1)}}}; // br1: k from sa_s
        k_gemm8<<<dim3(512,4), 64, 0, stream>>>(qj, 0, 0, 512, 0);
        SAJobs sj = {{Q8(0), Q8(1)}, {K8(0), K8(1)}, {ATW(0), ATW(1)}};
        k_sscm_attn<<<dim3(64,2), 64, 0, stream>>>(sj);
        ConvJobs vj = {};
        vj.j[0] = {sa_q, nullptr, cavw, cavb, nullptr, nullptr, nullptr, B[4], 0};
        vj.j[1] = {sa_s, nullptr, cavw, cavb, nullptr, nullptr, nullptr, B[5], 0};
        k_convm<<<dim3(4,8,16), 512, 0, stream>>>(vj, 1.f);
        SPJobs pj = {{ATW(0), ATW(1)}, {B[4], B[5]}, {B[6], B[7]}};
        k_sscm_apply<<<dim3(4096,2), 256, 0, stream>>>(pj);
        ConvJobs aj = {};
        aj.j[0] = {B[6], nullptr, capw, capb, nullptr, nullptr, nullptr, ca_s, CF_RELU};
        aj.j[1] = {B[7], nullptr, capw, capb, nullptr, nullptr, nullptr, ca_q, CF_RELU};
        k_convm<<<dim3(4,8,16), 512, 0, stream>>>(aj, 1.f);
    }

    // ================= PIXEL =================
    if (paired_pixel){
        ConvJobs qkvj = {};
        qkvj.j[0] = {sa_s, nullptr, pqw, pqb, nullptr, nullptr, nullptr, B[4],  CF_SPLIT|CF_TRANS};
        qkvj.j[1] = {ca_q, nullptr, pkw, pkb, nullptr, nullptr, nullptr, B[5],  CF_SPLIT|CF_TRANS};
        qkvj.j[2] = {ca_q, nullptr, pvw, pvb, nullptr, nullptr, nullptr, B[6],  CF_SPLIT};
        qkvj.j[3] = {sa_q, nullptr, pqw, pqb, nullptr, nullptr, nullptr, B[8],  CF_SPLIT|CF_TRANS};
        qkvj.j[4] = {ca_s, nullptr, pkw, pkb, nullptr, nullptr, nullptr, B[9],  CF_SPLIT|CF_TRANS};
        qkvj.j[5] = {ca_s, nullptr, pvw, pvb, nullptr, nullptr, nullptr, B[10], CF_SPLIT};
        k_convm<<<dim3(4,8,48), 512, 0, stream>>>(qkvj, 1.f);
        if (!has_dsplit){
            ZJobs zj = {{B[7], B[11]}};
            k_zero<<<dim3(4096,2), 256, 0, stream>>>(zj);
        }
        float* o2a = has_dsplit ? B[12] : nullptr;
        float* o2b = has_dsplit ? B[13] : nullptr;
        PixJobs pxj = {{{(const unsigned*)B[4], (const unsigned*)B[5], (const unsigned*)B[6],  B[7],  o2a},
                        {(const unsigned*)B[8], (const unsigned*)B[9], (const unsigned*)B[10], B[11], o2b}}};
        k_pixel_mfma<<<dim3(8,16,8), 256, 0, stream>>>(pxj);
        ConvJobs ppj = {};
        ppj.j[0] = {B[7],  o2a, ppw, ppb, sa_s, nullptr, nullptr, out0, CF_RES};
        ppj.j[1] = {B[11], o2b, ppw, ppb, sa_q, nullptr, nullptr, out1, CF_RES};
        k_convm<<<dim3(4,8,16), 512, 0, stream>>>(ppj, 1.f);
        LnJobs lj = {{out0, out1}, {B[4], B[8]}};
        k_ln_pix<<<dim3(2048,2), 64, 0, stream>>>(lj, plng, plnb);
        ConvJobs lnj = {};
        lnj.j[0] = {B[4], nullptr, plinw, plinb, nullptr, nullptr, nullptr, out0, CF_RELU};
        lnj.j[1] = {B[8], nullptr, plinw, plinb, nullptr, nullptr, nullptr, out1, CF_RELU};
        k_convm<<<dim3(4,8,16), 512, 0, stream>>>(lnj, 1.f);
    } else {
        auto pixel1 = [&](const float* x1, const float* x2, float* out){
            ConvJobs qkvj = {};
            qkvj.j[0] = {x1, nullptr, pqw, pqb, nullptr, nullptr, nullptr, B[4], CF_SPLIT|CF_TRANS};
            qkvj.j[1] = {x2, nullptr, pkw, pkb, nullptr, nullptr, nullptr, B[5], CF_SPLIT|CF_TRANS};
            qkvj.j[2] = {x2, nullptr, pvw, pvb, nullptr, nullptr, nullptr, B[6], CF_SPLIT};
            k_convm<<<dim3(4,8,24), 512, 0, stream>>>(qkvj, 1.f);
            ZJobs zj = {{B[7], B[7]}};
            k_zero<<<dim3(4096,1), 256, 0, stream>>>(zj);
            PixJobs pxj = {{{(const unsigned*)B[4], (const unsigned*)B[5], (const unsigned*)B[6], B[7], nullptr},
                            {(const unsigned*)B[4], (const unsigned*)B[5], (const unsigned*)B[6], B[7], nullptr}}};
            k_pixel_mfma<<<dim3(8,8,8), 256, 0, stream>>>(pxj);
            ConvJobs ppj = {};
            ppj.j[0] = {B[7], nullptr, ppw, ppb, x1, nullptr, nullptr, out, CF_RES};
            k_convm<<<dim3(4,8,8), 512, 0, stream>>>(ppj, 1.f);
            LnJobs lj = {{out, out}, {B[4], B[4]}};
            k_ln_pix<<<dim3(2048,1), 64, 0, stream>>>(lj, plng, plnb);
            ConvJobs lnj = {};
            lnj.j[0] = {B[4], nullptr, plinw, plinb, nullptr, nullptr, nullptr, out, CF_RELU};
            k_convm<<<dim3(4,8,8), 512, 0, stream>>>(lnj, 1.f);
        };
        pixel1(sa_s, ca_q, out0);
        pixel1(sa_q, ca_s, out1);
    }

    (void)in_sizes; (void)n_in; (void)out_size;
}